// Round 1
// baseline (1269.146 us; speedup 1.0000x reference)
//
#include <hip/hip_runtime.h>
#include <hip/hip_bf16.h>

#define N_NODES 50000
#define N_EDGES 1600000
#define NG      256
#define HD      128

// ---------------- CSR build ----------------

__global__ void count_kernel(const int* __restrict__ dst, int* __restrict__ counts) {
    int e = blockIdx.x * 256 + threadIdx.x;
    if (e < N_EDGES) atomicAdd(&counts[dst[e]], 1);
}

__global__ void deg_kernel(const int* __restrict__ counts, float* __restrict__ degInv) {
    int n = blockIdx.x * 256 + threadIdx.x;
    if (n < N_NODES) degInv[n] = 1.0f / fmaxf((float)counts[n], 1.0f);
}

// inclusive scan, 1024 elems per block (256 thr x 4)
__global__ void scan1_kernel(const int* __restrict__ counts, int* __restrict__ incl,
                             int* __restrict__ blk_tot) {
    __shared__ int sh[256];
    int b = blockIdx.x, t = threadIdx.x;
    int base = b * 1024 + t * 4;
    int v0 = (base + 0 < N_NODES) ? counts[base + 0] : 0;
    int v1 = (base + 1 < N_NODES) ? counts[base + 1] : 0;
    int v2 = (base + 2 < N_NODES) ? counts[base + 2] : 0;
    int v3 = (base + 3 < N_NODES) ? counts[base + 3] : 0;
    int s0 = v0, s1 = s0 + v1, s2 = s1 + v2, s3 = s2 + v3;
    sh[t] = s3;
    __syncthreads();
    for (int off = 1; off < 256; off <<= 1) {
        int x = (t >= off) ? sh[t - off] : 0;
        __syncthreads();
        sh[t] += x;
        __syncthreads();
    }
    int excl = sh[t] - s3;
    if (base + 0 < N_NODES) incl[base + 0] = s0 + excl;
    if (base + 1 < N_NODES) incl[base + 1] = s1 + excl;
    if (base + 2 < N_NODES) incl[base + 2] = s2 + excl;
    if (base + 3 < N_NODES) incl[base + 3] = s3 + excl;
    if (t == 255) blk_tot[b] = sh[255];
}

__global__ void scan2_kernel(const int* __restrict__ blk_tot, int* __restrict__ blk_off, int nb) {
    if (threadIdx.x == 0 && blockIdx.x == 0) {
        int run = 0;
        for (int i = 0; i < nb; ++i) { int v = blk_tot[i]; blk_off[i] = run; run += v; }
    }
}

__global__ void scan3_kernel(const int* __restrict__ incl, const int* __restrict__ blk_off,
                             int* __restrict__ row_ptr) {
    int n = blockIdx.x * 256 + threadIdx.x;
    if (n < N_NODES) {
        row_ptr[n + 1] = incl[n] + blk_off[n >> 10];
        if (n == 0) row_ptr[0] = 0;
    }
}

__global__ void fill_kernel(const int* __restrict__ src, const int* __restrict__ dst,
                            const int* __restrict__ row_ptr, int* __restrict__ cursor,
                            int* __restrict__ col) {
    int e = blockIdx.x * 256 + threadIdx.x;
    if (e < N_EDGES) {
        int d = dst[e];
        int pos = row_ptr[d] + atomicAdd(&cursor[d], 1);
        col[pos] = src[e];
    }
}

// ---------------- mean aggregation: one wave per node ----------------

__global__ void agg_kernel(const float* __restrict__ X, const int* __restrict__ row_ptr,
                           const int* __restrict__ col, const float* __restrict__ degInv,
                           float* __restrict__ out) {
    int w = (blockIdx.x * blockDim.x + threadIdx.x) >> 6;
    int lane = threadIdx.x & 63;
    if (w >= N_NODES) return;
    int beg = row_ptr[w], end = row_ptr[w + 1];
    const float2* __restrict__ X2 = (const float2*)X;
    float2 acc = {0.f, 0.f};
    #pragma unroll 2
    for (int j = beg; j < end; ++j) {
        int s = col[j];
        float2 v = X2[s * 64 + lane];
        acc.x += v.x; acc.y += v.y;
    }
    float inv = degInv[w];
    acc.x *= inv; acc.y *= inv;
    ((float2*)out)[w * 64 + lane] = acc;
}

// ---------------- fused dual-matmul: out = relu(A1@W1 + A2@W2 + b) ----------------
// A1,A2: [N,128] row-major. W1,W2: [128,128] row-major [k][n]. out: [N,128].

#define BM 64
#define BK 32

__global__ __launch_bounds__(256) void gemm_relu_kernel(
        const float* __restrict__ A1, const float* __restrict__ A2,
        const float* __restrict__ W1, const float* __restrict__ W2,
        const float* __restrict__ bias, float* __restrict__ out) {
    __shared__ float As[BM][BK + 1];      // +1 pad: ty-stride 132 -> distinct banks
    __shared__ float Ws[BK][128];
    int tid = threadIdx.x;
    int row0 = blockIdx.x * BM;
    int ty = tid >> 4;   // 0..15 -> rows ty*4 .. +4
    int tx = tid & 15;   // cols tx + 16*j
    float acc[4][8];
    #pragma unroll
    for (int i = 0; i < 4; ++i)
        #pragma unroll
        for (int j = 0; j < 8; ++j) acc[i][j] = 0.f;

    for (int kc = 0; kc < 8; ++kc) {
        int k0 = kc * BK;
        const float* Asrc = (k0 < 128) ? A1 : A2;
        const float* Wsrc = (k0 < 128) ? W1 : W2;
        int kk0 = k0 & 127;
        // stage A tile: 64 rows x 32 k
        {
            int r = tid >> 3, f4 = tid & 7;
            #pragma unroll
            for (int p = 0; p < 2; ++p) {
                int rr = r + p * 32;
                int gr = min(row0 + rr, N_NODES - 1);
                float4 v = *(const float4*)&Asrc[gr * HD + kk0 + f4 * 4];
                *(float4*)&As[rr][f4 * 4] = v;
            }
        }
        // stage W tile: 32 k x 128 cols
        {
            int wr = tid >> 5, wf4 = tid & 31;
            #pragma unroll
            for (int p = 0; p < 4; ++p) {
                int kk = wr + p * 8;
                float4 v = *(const float4*)&Wsrc[(kk0 + kk) * HD + wf4 * 4];
                *(float4*)&Ws[kk][wf4 * 4] = v;
            }
        }
        __syncthreads();
        #pragma unroll
        for (int kk = 0; kk < BK; ++kk) {
            float a[4], w[8];
            #pragma unroll
            for (int i = 0; i < 4; ++i) a[i] = As[ty * 4 + i][kk];
            #pragma unroll
            for (int j = 0; j < 8; ++j) w[j] = Ws[kk][tx + 16 * j];
            #pragma unroll
            for (int i = 0; i < 4; ++i)
                #pragma unroll
                for (int j = 0; j < 8; ++j)
                    acc[i][j] += a[i] * w[j];
        }
        __syncthreads();
    }
    #pragma unroll
    for (int i = 0; i < 4; ++i) {
        int gr = row0 + ty * 4 + i;
        if (gr < N_NODES) {
            #pragma unroll
            for (int j = 0; j < 8; ++j) {
                int c = tx + 16 * j;
                float v = acc[i][j] + bias[c];
                out[gr * HD + c] = fmaxf(v, 0.f);
            }
        }
    }
}

// ---------------- per-graph pooling (batch is sorted) ----------------

__global__ void pool_kernel(const float* __restrict__ h, const int* __restrict__ batch,
                            float* __restrict__ p) {
    int g = blockIdx.x, t = threadIdx.x;  // 128 threads
    int lo = 0, hi = N_NODES;
    while (lo < hi) { int mid = (lo + hi) >> 1; if (batch[mid] < g) lo = mid + 1; else hi = mid; }
    int start = lo;
    hi = N_NODES;
    while (lo < hi) { int mid = (lo + hi) >> 1; if (batch[mid] < g + 1) lo = mid + 1; else hi = mid; }
    int end = lo;
    float s = 0.f;
    for (int n = start; n < end; ++n) s += h[n * HD + t];
    p[g * HD + t] = s;
}

// ---------------- head: BN + MLP + softmax ----------------

__global__ void head_kernel(const float* __restrict__ p0, const float* __restrict__ p1,
                            const float* __restrict__ gamma, const float* __restrict__ beta,
                            const float* __restrict__ rm, const float* __restrict__ rv,
                            const float* __restrict__ W1, const float* __restrict__ b1,
                            const float* __restrict__ W2, const float* __restrict__ b2,
                            float* __restrict__ out) {
    __shared__ float xb[256];
    __shared__ float hh[128];
    __shared__ float oo[10];
    int g = blockIdx.x, t = threadIdx.x;  // 128 threads
    {
        float v0 = p0[g * HD + t];
        float v1 = p1[g * HD + t];
        int d1 = t + 128;
        xb[t]  = (v0 - rm[t])  * rsqrtf(rv[t]  + 1e-5f) * gamma[t]  + beta[t];
        xb[d1] = (v1 - rm[d1]) * rsqrtf(rv[d1] + 1e-5f) * gamma[d1] + beta[d1];
    }
    __syncthreads();
    float acc = b1[t];
    for (int d = 0; d < 256; ++d) acc += xb[d] * W1[d * HD + t];
    hh[t] = fmaxf(acc, 0.f);
    __syncthreads();
    if (t < 10) {
        float o = b2[t];
        for (int d = 0; d < 128; ++d) o += hh[d] * W2[d * 10 + t];
        oo[t] = o;
    }
    __syncthreads();
    if (t < 10) {
        float m = oo[0];
        for (int c = 1; c < 10; ++c) m = fmaxf(m, oo[c]);
        float sum = 0.f;
        for (int c = 0; c < 10; ++c) sum += expf(oo[c] - m);
        out[g * 10 + t] = expf(oo[t] - m) / sum;
    }
}

// ---------------- launcher ----------------

extern "C" void kernel_launch(void* const* d_in, const int* in_sizes, int n_in,
                              void* d_out, int out_size, void* d_ws, size_t ws_size,
                              hipStream_t stream) {
    const float* x    = (const float*)d_in[0];
    const int*   ei   = (const int*)d_in[1];
    const int*   batch = (const int*)d_in[2];
    const int*   src = ei;
    const int*   dst = ei + N_EDGES;

    const float* b0_Wl1 = (const float*)d_in[4];
    const float* b0_Wr1 = (const float*)d_in[5];
    const float* b0_b1  = (const float*)d_in[6];
    const float* b0_Wl2 = (const float*)d_in[7];
    const float* b0_Wr2 = (const float*)d_in[8];
    const float* b0_b2  = (const float*)d_in[9];
    const float* b0_Wlin = (const float*)d_in[10];
    const float* b0_blin = (const float*)d_in[11];
    const float* b1_Wl1 = (const float*)d_in[12];
    const float* b1_Wr1 = (const float*)d_in[13];
    const float* b1_b1  = (const float*)d_in[14];
    const float* b1_Wl2 = (const float*)d_in[15];
    const float* b1_Wr2 = (const float*)d_in[16];
    const float* b1_b2  = (const float*)d_in[17];
    const float* b1_Wlin = (const float*)d_in[18];
    const float* b1_blin = (const float*)d_in[19];
    const float* bn_gamma = (const float*)d_in[20];
    const float* bn_beta  = (const float*)d_in[21];
    const float* bn_rm    = (const float*)d_in[22];
    const float* bn_rv    = (const float*)d_in[23];
    const float* lin1_W = (const float*)d_in[24];
    const float* lin1_b = (const float*)d_in[25];
    const float* lin2_W = (const float*)d_in[26];
    const float* lin2_b = (const float*)d_in[27];

    float* out = (float*)d_out;

    // workspace layout (256B aligned chunks)
    char* ws = (char*)d_ws;
    size_t off = 0;
    auto alloc = [&](size_t bytes) { void* p = ws + off; off += (bytes + 255) & ~size_t(255); return p; };
    float* degInv = (float*)alloc(N_NODES * 4);
    int* counts   = (int*)alloc(N_NODES * 4);
    int* cursor   = (int*)alloc(N_NODES * 4);
    int* row_ptr  = (int*)alloc((N_NODES + 1) * 4);
    int* incl     = (int*)alloc(N_NODES * 4);
    int* blk_tot  = (int*)alloc(64 * 4);
    int* blk_off  = (int*)alloc(64 * 4);
    int* col      = (int*)alloc(N_EDGES * 4);
    float* A = (float*)alloc((size_t)N_NODES * HD * 4);
    float* B = (float*)alloc((size_t)N_NODES * HD * 4);
    float* C = (float*)alloc((size_t)N_NODES * HD * 4);
    float* D = (float*)alloc((size_t)N_NODES * HD * 4);
    float* p0 = (float*)alloc(NG * HD * 4);
    float* p1 = (float*)alloc(NG * HD * 4);
    (void)ws_size; (void)n_in; (void)in_sizes; (void)out_size;

    // counts and cursor are adjacent: zero both
    hipMemsetAsync(counts, 0, 2 * ((N_NODES * 4 + 255) & ~size_t(255)), stream);

    const int EB = (N_EDGES + 255) / 256;
    const int NB1024 = (N_NODES + 1023) / 1024;
    const int NB256 = (N_NODES + 255) / 256;
    count_kernel<<<EB, 256, 0, stream>>>(dst, counts);
    deg_kernel<<<NB256, 256, 0, stream>>>(counts, degInv);
    scan1_kernel<<<NB1024, 256, 0, stream>>>(counts, incl, blk_tot);
    scan2_kernel<<<1, 64, 0, stream>>>(blk_tot, blk_off, NB1024);
    scan3_kernel<<<NB256, 256, 0, stream>>>(incl, blk_off, row_ptr);
    fill_kernel<<<EB, 256, 0, stream>>>(src, dst, row_ptr, cursor, col);

    const int AGG_B = (N_NODES * 64 + 255) / 256;
    const int GEMM_B = (N_NODES + BM - 1) / BM;

    // block 0
    agg_kernel<<<AGG_B, 256, 0, stream>>>(x, row_ptr, col, degInv, A);
    gemm_relu_kernel<<<GEMM_B, 256, 0, stream>>>(A, x, b0_Wl1, b0_Wr1, b0_b1, B);   // h1
    agg_kernel<<<AGG_B, 256, 0, stream>>>(B, row_ptr, col, degInv, A);
    gemm_relu_kernel<<<GEMM_B, 256, 0, stream>>>(A, B, b0_Wl2, b0_Wr2, b0_b2, C);   // h2
    gemm_relu_kernel<<<GEMM_B, 256, 0, stream>>>(B, C, b0_Wlin, b0_Wlin + 128 * HD, b0_blin, D); // hb0
    pool_kernel<<<NG, HD, 0, stream>>>(D, batch, p0);
    // block 1
    agg_kernel<<<AGG_B, 256, 0, stream>>>(D, row_ptr, col, degInv, A);
    gemm_relu_kernel<<<GEMM_B, 256, 0, stream>>>(A, D, b1_Wl1, b1_Wr1, b1_b1, B);   // h1b
    agg_kernel<<<AGG_B, 256, 0, stream>>>(B, row_ptr, col, degInv, A);
    gemm_relu_kernel<<<GEMM_B, 256, 0, stream>>>(A, B, b1_Wl2, b1_Wr2, b1_b2, C);   // h2b
    gemm_relu_kernel<<<GEMM_B, 256, 0, stream>>>(B, C, b1_Wlin, b1_Wlin + 128 * HD, b1_blin, D); // hb1
    pool_kernel<<<NG, HD, 0, stream>>>(D, batch, p1);
    // head
    head_kernel<<<NG, HD, 0, stream>>>(p0, p1, bn_gamma, bn_beta, bn_rm, bn_rv,
                                       lin1_W, lin1_b, lin2_W, lin2_b, out);
}

// Round 2
// 900.419 us; speedup vs baseline: 1.4095x; 1.4095x over previous
//
#include <hip/hip_runtime.h>
#include <hip/hip_bf16.h>

#define N_NODES 50000
#define N_EDGES 1600000
#define NG      256
#define HD      128

typedef __attribute__((ext_vector_type(8))) __bf16 bf16x8;
typedef __attribute__((ext_vector_type(4))) float f32x4;

// ---------------- CSR build ----------------

__global__ void count_kernel(const int* __restrict__ dst, int* __restrict__ counts) {
    int e = blockIdx.x * 256 + threadIdx.x;
    if (e < N_EDGES) atomicAdd(&counts[dst[e]], 1);
}

__global__ void deg_kernel(const int* __restrict__ counts, float* __restrict__ degInv) {
    int n = blockIdx.x * 256 + threadIdx.x;
    if (n < N_NODES) degInv[n] = 1.0f / fmaxf((float)counts[n], 1.0f);
}

__global__ void scan1_kernel(const int* __restrict__ counts, int* __restrict__ incl,
                             int* __restrict__ blk_tot) {
    __shared__ int sh[256];
    int b = blockIdx.x, t = threadIdx.x;
    int base = b * 1024 + t * 4;
    int v0 = (base + 0 < N_NODES) ? counts[base + 0] : 0;
    int v1 = (base + 1 < N_NODES) ? counts[base + 1] : 0;
    int v2 = (base + 2 < N_NODES) ? counts[base + 2] : 0;
    int v3 = (base + 3 < N_NODES) ? counts[base + 3] : 0;
    int s0 = v0, s1 = s0 + v1, s2 = s1 + v2, s3 = s2 + v3;
    sh[t] = s3;
    __syncthreads();
    for (int off = 1; off < 256; off <<= 1) {
        int x = (t >= off) ? sh[t - off] : 0;
        __syncthreads();
        sh[t] += x;
        __syncthreads();
    }
    int excl = sh[t] - s3;
    if (base + 0 < N_NODES) incl[base + 0] = s0 + excl;
    if (base + 1 < N_NODES) incl[base + 1] = s1 + excl;
    if (base + 2 < N_NODES) incl[base + 2] = s2 + excl;
    if (base + 3 < N_NODES) incl[base + 3] = s3 + excl;
    if (t == 255) blk_tot[b] = sh[255];
}

__global__ void scan2_kernel(const int* __restrict__ blk_tot, int* __restrict__ blk_off, int nb) {
    if (threadIdx.x == 0 && blockIdx.x == 0) {
        int run = 0;
        for (int i = 0; i < nb; ++i) { int v = blk_tot[i]; blk_off[i] = run; run += v; }
    }
}

__global__ void scan3_kernel(const int* __restrict__ incl, const int* __restrict__ blk_off,
                             int* __restrict__ row_ptr) {
    int n = blockIdx.x * 256 + threadIdx.x;
    if (n < N_NODES) {
        row_ptr[n + 1] = incl[n] + blk_off[n >> 10];
        if (n == 0) row_ptr[0] = 0;
    }
}

__global__ void fill_kernel(const int* __restrict__ src, const int* __restrict__ dst,
                            const int* __restrict__ row_ptr, int* __restrict__ cursor,
                            int* __restrict__ col) {
    int e = blockIdx.x * 256 + threadIdx.x;
    if (e < N_EDGES) {
        int d = dst[e];
        int pos = row_ptr[d] + atomicAdd(&cursor[d], 1);
        col[pos] = src[e];
    }
}

// ---------------- fp32 -> bf16 cast of x ----------------

__global__ void cast_x_kernel(const float* __restrict__ x, __hip_bfloat16* __restrict__ xb) {
    int i = blockIdx.x * 256 + threadIdx.x;  // one float4 per thread
    if (i < N_NODES * 32) {
        float4 v = ((const float4*)x)[i];
        float2 lo = {v.x, v.y}, hi = {v.z, v.w};
        ((__hip_bfloat162*)xb)[i * 2 + 0] = __float22bfloat162_rn(lo);
        ((__hip_bfloat162*)xb)[i * 2 + 1] = __float22bfloat162_rn(hi);
    }
}

// ---------------- weight pack: [256][128] fp32 -> MFMA B-frag-linear bf16 ----------------
// layout: Bp[g][kk][n][lane][i] ; element = W[k][col], k = kk*32 + (lane>>4)*8 + i,
// col = n*16 + (lane&15). Each wave reads (kk,n) frag as 64 consecutive 16B chunks.

__global__ void pack_w_kernel(const float* __restrict__ p0a, const float* __restrict__ p0b,
                              const float* __restrict__ p1a, const float* __restrict__ p1b,
                              const float* __restrict__ p2a, const float* __restrict__ p2b,
                              const float* __restrict__ p3a, const float* __restrict__ p3b,
                              const float* __restrict__ p4a, const float* __restrict__ p4b,
                              const float* __restrict__ p5a, const float* __restrict__ p5b,
                              __hip_bfloat16* __restrict__ out) {
    int idx = blockIdx.x * 256 + threadIdx.x;
    if (idx >= 6 * 32768) return;
    int g = idx >> 15;
    int r = idx & 32767;
    int i = r & 7;
    int k = ((r >> 12) & 7) * 32 + ((r >> 7) & 3) * 8 + i;
    int col = ((r >> 9) & 7) * 16 + ((r >> 3) & 15);
    const float* a; const float* b;
    switch (g) {
        case 0: a = p0a; b = p0b; break;
        case 1: a = p1a; b = p1b; break;
        case 2: a = p2a; b = p2b; break;
        case 3: a = p3a; b = p3b; break;
        case 4: a = p4a; b = p4b; break;
        default: a = p5a; b = p5b; break;
    }
    const float* src = (k < 128) ? a : b;
    int kk2 = k & 127;
    out[idx] = __float2bfloat16(src[kk2 * HD + col]);
}

// ---------------- mean aggregation (bf16 in/out, fp32 accum) ----------------

__global__ void agg_kernel(const __hip_bfloat16* __restrict__ X, const int* __restrict__ row_ptr,
                           const int* __restrict__ col, const float* __restrict__ degInv,
                           __hip_bfloat16* __restrict__ out) {
    int w = (blockIdx.x * blockDim.x + threadIdx.x) >> 6;
    int lane = threadIdx.x & 63;
    if (w >= N_NODES) return;
    int beg = row_ptr[w], end = row_ptr[w + 1];
    const __hip_bfloat162* __restrict__ X2 = (const __hip_bfloat162*)X;
    float2 acc = {0.f, 0.f};
    #pragma unroll 2
    for (int j = beg; j < end; ++j) {
        int s = col[j];
        float2 v = __bfloat1622float2(X2[s * 64 + lane]);
        acc.x += v.x; acc.y += v.y;
    }
    float inv = degInv[w];
    float2 rr = {acc.x * inv, acc.y * inv};
    ((__hip_bfloat162*)out)[w * 64 + lane] = __float22bfloat162_rn(rr);
}

// ---------------- dual-matmul via MFMA: out = relu([A1|A2] @ Wpack + b) ----------------
// Block = 256 thr = 4 waves; each wave computes 16 rows x 128 cols. No LDS, no barriers.

__global__ __launch_bounds__(256) void gemm_mfma_kernel(
        const __hip_bfloat16* __restrict__ A1, const __hip_bfloat16* __restrict__ A2,
        const __hip_bfloat16* __restrict__ Bp, const float* __restrict__ bias,
        __hip_bfloat16* __restrict__ out) {
    int lane = threadIdx.x & 63;
    int wave = threadIdx.x >> 6;
    int row0 = blockIdx.x * 64 + wave * 16;
    int arow = row0 + (lane & 15);
    int arow_c = min(arow, N_NODES - 1);
    int kb = (lane >> 4) << 3;  // k-octet base: 0,8,16,24
    f32x4 acc[8] = {};
    const bf16x8* __restrict__ Bp8 = (const bf16x8*)Bp;
    #pragma unroll
    for (int kk = 0; kk < 8; ++kk) {
        const __hip_bfloat16* __restrict__ As = (kk < 4) ? A1 : A2;
        int k0 = (kk & 3) * 32 + kb;
        bf16x8 af = *(const bf16x8*)&As[arow_c * HD + k0];
        #pragma unroll
        for (int n = 0; n < 8; ++n) {
            bf16x8 bf = Bp8[(kk * 8 + n) * 64 + lane];
            acc[n] = __builtin_amdgcn_mfma_f32_16x16x32_bf16(af, bf, acc[n], 0, 0, 0);
        }
    }
    // C/D layout: col = lane&15, row = (lane>>4)*4 + i  [verified m89/m91]
    int crow0 = row0 + ((lane >> 4) << 2);
    int ccol = lane & 15;
    #pragma unroll
    for (int n = 0; n < 8; ++n) {
        int c = n * 16 + ccol;
        float b = bias[c];
        #pragma unroll
        for (int i = 0; i < 4; ++i) {
            int row = crow0 + i;
            if (row < N_NODES) {
                float v = acc[n][i] + b;
                out[row * HD + c] = __float2bfloat16(fmaxf(v, 0.f));
            }
        }
    }
}

// ---------------- per-graph pooling (batch sorted), bf16 in fp32 out ----------------

__global__ void pool_kernel(const __hip_bfloat16* __restrict__ h, const int* __restrict__ batch,
                            float* __restrict__ p) {
    int g = blockIdx.x, t = threadIdx.x;  // 128 threads
    int lo = 0, hi = N_NODES;
    while (lo < hi) { int mid = (lo + hi) >> 1; if (batch[mid] < g) lo = mid + 1; else hi = mid; }
    int start = lo;
    hi = N_NODES;
    while (lo < hi) { int mid = (lo + hi) >> 1; if (batch[mid] < g + 1) lo = mid + 1; else hi = mid; }
    int end = lo;
    float s = 0.f;
    for (int n = start; n < end; ++n) s += __bfloat162float(h[n * HD + t]);
    p[g * HD + t] = s;
}

// ---------------- head: BN + MLP + softmax (fp32) ----------------

__global__ void head_kernel(const float* __restrict__ p0, const float* __restrict__ p1,
                            const float* __restrict__ gamma, const float* __restrict__ beta,
                            const float* __restrict__ rm, const float* __restrict__ rv,
                            const float* __restrict__ W1, const float* __restrict__ b1,
                            const float* __restrict__ W2, const float* __restrict__ b2,
                            float* __restrict__ out) {
    __shared__ float xb[256];
    __shared__ float hh[128];
    __shared__ float oo[10];
    int g = blockIdx.x, t = threadIdx.x;  // 128 threads
    {
        float v0 = p0[g * HD + t];
        float v1 = p1[g * HD + t];
        int d1 = t + 128;
        xb[t]  = (v0 - rm[t])  * rsqrtf(rv[t]  + 1e-5f) * gamma[t]  + beta[t];
        xb[d1] = (v1 - rm[d1]) * rsqrtf(rv[d1] + 1e-5f) * gamma[d1] + beta[d1];
    }
    __syncthreads();
    float acc = b1[t];
    for (int d = 0; d < 256; ++d) acc += xb[d] * W1[d * HD + t];
    hh[t] = fmaxf(acc, 0.f);
    __syncthreads();
    if (t < 10) {
        float o = b2[t];
        for (int d = 0; d < 128; ++d) o += hh[d] * W2[d * 10 + t];
        oo[t] = o;
    }
    __syncthreads();
    if (t < 10) {
        float m = oo[0];
        for (int c = 1; c < 10; ++c) m = fmaxf(m, oo[c]);
        float sum = 0.f;
        for (int c = 0; c < 10; ++c) sum += expf(oo[c] - m);
        out[g * 10 + t] = expf(oo[t] - m) / sum;
    }
}

// ---------------- launcher ----------------

extern "C" void kernel_launch(void* const* d_in, const int* in_sizes, int n_in,
                              void* d_out, int out_size, void* d_ws, size_t ws_size,
                              hipStream_t stream) {
    const float* x     = (const float*)d_in[0];
    const int*   ei    = (const int*)d_in[1];
    const int*   batch = (const int*)d_in[2];
    const int*   src = ei;
    const int*   dst = ei + N_EDGES;

    const float* b0_Wl1 = (const float*)d_in[4];
    const float* b0_Wr1 = (const float*)d_in[5];
    const float* b0_b1  = (const float*)d_in[6];
    const float* b0_Wl2 = (const float*)d_in[7];
    const float* b0_Wr2 = (const float*)d_in[8];
    const float* b0_b2  = (const float*)d_in[9];
    const float* b0_Wlin = (const float*)d_in[10];
    const float* b0_blin = (const float*)d_in[11];
    const float* b1_Wl1 = (const float*)d_in[12];
    const float* b1_Wr1 = (const float*)d_in[13];
    const float* b1_b1  = (const float*)d_in[14];
    const float* b1_Wl2 = (const float*)d_in[15];
    const float* b1_Wr2 = (const float*)d_in[16];
    const float* b1_b2  = (const float*)d_in[17];
    const float* b1_Wlin = (const float*)d_in[18];
    const float* b1_blin = (const float*)d_in[19];
    const float* bn_gamma = (const float*)d_in[20];
    const float* bn_beta  = (const float*)d_in[21];
    const float* bn_rm    = (const float*)d_in[22];
    const float* bn_rv    = (const float*)d_in[23];
    const float* lin1_W = (const float*)d_in[24];
    const float* lin1_b = (const float*)d_in[25];
    const float* lin2_W = (const float*)d_in[26];
    const float* lin2_b = (const float*)d_in[27];

    float* out = (float*)d_out;

    char* ws = (char*)d_ws;
    size_t off = 0;
    auto alloc = [&](size_t bytes) { void* p = ws + off; off += (bytes + 255) & ~size_t(255); return p; };
    float* degInv = (float*)alloc(N_NODES * 4);
    int* counts   = (int*)alloc(N_NODES * 4);
    int* cursor   = (int*)alloc(N_NODES * 4);
    int* row_ptr  = (int*)alloc((N_NODES + 1) * 4);
    int* incl     = (int*)alloc(N_NODES * 4);
    int* blk_tot  = (int*)alloc(64 * 4);
    int* blk_off  = (int*)alloc(64 * 4);
    int* col      = (int*)alloc(N_EDGES * 4);
    __hip_bfloat16* Xb = (__hip_bfloat16*)alloc((size_t)N_NODES * HD * 2);
    __hip_bfloat16* A  = (__hip_bfloat16*)alloc((size_t)N_NODES * HD * 2);
    __hip_bfloat16* B  = (__hip_bfloat16*)alloc((size_t)N_NODES * HD * 2);
    __hip_bfloat16* C  = (__hip_bfloat16*)alloc((size_t)N_NODES * HD * 2);
    __hip_bfloat16* D  = (__hip_bfloat16*)alloc((size_t)N_NODES * HD * 2);
    __hip_bfloat16* Bpack = (__hip_bfloat16*)alloc(6 * 32768 * 2);
    float* p0 = (float*)alloc(NG * HD * 4);
    float* p1 = (float*)alloc(NG * HD * 4);
    (void)ws_size; (void)n_in; (void)in_sizes; (void)out_size;

    // counts and cursor are adjacent: zero both
    hipMemsetAsync(counts, 0, 2 * ((N_NODES * 4 + 255) & ~size_t(255)), stream);

    const int EB = (N_EDGES + 255) / 256;
    const int NB1024 = (N_NODES + 1023) / 1024;
    const int NB256 = (N_NODES + 255) / 256;
    cast_x_kernel<<<(N_NODES * 32 + 255) / 256, 256, 0, stream>>>(x, Xb);
    pack_w_kernel<<<(6 * 32768 + 255) / 256, 256, 0, stream>>>(
        b0_Wl1, b0_Wr1, b0_Wl2, b0_Wr2, b0_Wlin, b0_Wlin + 128 * HD,
        b1_Wl1, b1_Wr1, b1_Wl2, b1_Wr2, b1_Wlin, b1_Wlin + 128 * HD, Bpack);
    count_kernel<<<EB, 256, 0, stream>>>(dst, counts);
    deg_kernel<<<NB256, 256, 0, stream>>>(counts, degInv);
    scan1_kernel<<<NB1024, 256, 0, stream>>>(counts, incl, blk_tot);
    scan2_kernel<<<1, 64, 0, stream>>>(blk_tot, blk_off, NB1024);
    scan3_kernel<<<NB256, 256, 0, stream>>>(incl, blk_off, row_ptr);
    fill_kernel<<<EB, 256, 0, stream>>>(src, dst, row_ptr, cursor, col);

    const int AGG_B = (N_NODES * 64 + 255) / 256;
    const int GEMM_B = (N_NODES + 63) / 64;

    __hip_bfloat16* Bp0 = Bpack + 0 * 32768;
    __hip_bfloat16* Bp1 = Bpack + 1 * 32768;
    __hip_bfloat16* Bp2 = Bpack + 2 * 32768;
    __hip_bfloat16* Bp3 = Bpack + 3 * 32768;
    __hip_bfloat16* Bp4 = Bpack + 4 * 32768;
    __hip_bfloat16* Bp5 = Bpack + 5 * 32768;

    // block 0
    agg_kernel<<<AGG_B, 256, 0, stream>>>(Xb, row_ptr, col, degInv, A);
    gemm_mfma_kernel<<<GEMM_B, 256, 0, stream>>>(A, Xb, Bp0, b0_b1, B);   // h1
    agg_kernel<<<AGG_B, 256, 0, stream>>>(B, row_ptr, col, degInv, A);
    gemm_mfma_kernel<<<GEMM_B, 256, 0, stream>>>(A, B, Bp1, b0_b2, C);    // h2
    gemm_mfma_kernel<<<GEMM_B, 256, 0, stream>>>(B, C, Bp2, b0_blin, D);  // hb0 (JK cat)
    pool_kernel<<<NG, HD, 0, stream>>>(D, batch, p0);
    // block 1
    agg_kernel<<<AGG_B, 256, 0, stream>>>(D, row_ptr, col, degInv, A);
    gemm_mfma_kernel<<<GEMM_B, 256, 0, stream>>>(A, D, Bp3, b1_b1, B);    // h1
    agg_kernel<<<AGG_B, 256, 0, stream>>>(B, row_ptr, col, degInv, A);
    gemm_mfma_kernel<<<GEMM_B, 256, 0, stream>>>(A, B, Bp4, b1_b2, C);    // h2
    gemm_mfma_kernel<<<GEMM_B, 256, 0, stream>>>(B, C, Bp5, b1_blin, D);  // hb1 (JK cat)
    pool_kernel<<<NG, HD, 0, stream>>>(D, batch, p1);
    // head
    head_kernel<<<NG, HD, 0, stream>>>(p0, p1, bn_gamma, bn_beta, bn_rm, bn_rv,
                                       lin1_W, lin1_b, lin2_W, lin2_b, out);
}